// Round 2
// baseline (1619.699 us; speedup 1.0000x reference)
//
#include <hip/hip_runtime.h>

#define NN 100000
#define CC 128
#define KK 27
#define MM 60000
#define BBATCH 8
#define CRR 32
#define TM 64
#define NBLK ((MM + TM - 1) / TM)   // 938

typedef _Float16 half8 __attribute__((ext_vector_type(8)));
typedef float floatx4 __attribute__((ext_vector_type(4)));

struct __align__(8) Half4 { _Float16 x, y, z, w; };

// ---------------- conversion kernels ----------------

__global__ __launch_bounds__(256) void convert_x_kernel(
    const float* __restrict__ x, _Float16* __restrict__ xh) {
    int i = blockIdx.x * 256 + threadIdx.x;              // one float4 per thread
    if (i >= NN * (CC / 4)) return;
    float4 v = ((const float4*)x)[i];
    Half4 o;
    o.x = (_Float16)v.x; o.y = (_Float16)v.y;
    o.z = (_Float16)v.z; o.w = (_Float16)v.w;
    ((Half4*)xh)[i] = o;
}

// Wt[k][co][ci] = W[k][ci][co]  (transposed, f16)
__global__ __launch_bounds__(256) void convert_w_kernel(
    const float* __restrict__ W, _Float16* __restrict__ Wt) {
    int idx = blockIdx.x * 256 + threadIdx.x;            // over KK*CC*CC
    if (idx >= KK * CC * CC) return;
    int k = idx / (CC * CC);
    int rem = idx % (CC * CC);
    int co = rem / CC;
    int ci = rem % CC;
    Wt[idx] = (_Float16)W[(size_t)k * CC * CC + (size_t)ci * CC + co];
}

// ---------------- sparse conv: gather-MFMA-scatter ----------------
// grid = KK * NBLK blocks, 256 threads (4 waves). Each block: one k,
// 64 gathered rows x 128 cols output tile. out += via atomicAdd.
__global__ __launch_bounds__(256) void conv_kernel(
    const _Float16* __restrict__ xh,     // [NN][CC] f16
    const _Float16* __restrict__ Wt,     // [KK][CC(co)][CC(ci)] f16 transposed
    const int* __restrict__ in_idx,      // [KK][MM]
    const int* __restrict__ out_idx,     // [KK][MM]
    float* __restrict__ out)             // [NN][CC] f32, pre-zeroed
{
    __shared__ __align__(16) _Float16 Alds[TM][136];     // +8 pad: 272B rows -> 2-way banks
    __shared__ __align__(16) _Float16 Blds[CC][136];

    int k  = blockIdx.x / NBLK;
    int tb = blockIdx.x % NBLK;
    int m0 = tb * TM;
    int tid = threadIdx.x;

    // stage Wt[k] (128 rows x 256B) : 2048 16B-chunks over 256 threads
    const _Float16* Wk = Wt + (size_t)k * CC * CC;
    #pragma unroll
    for (int i = 0; i < 8; ++i) {
        int ch = tid + i * 256;
        int r = ch >> 4;
        int c8 = (ch & 15) << 3;
        *(half8*)&Blds[r][c8] = *(const half8*)&Wk[r * CC + c8];
    }
    // gather 64 A rows (16 threads x 16B per row)
    const int* ii = in_idx + (size_t)k * MM + m0;
    #pragma unroll
    for (int i = 0; i < 4; ++i) {
        int r = (tid >> 4) + i * 16;
        int c8 = (tid & 15) << 3;
        if (m0 + r < MM) {
            int g = ii[r];
            *(half8*)&Alds[r][c8] = *(const half8*)&xh[(size_t)g * CC + c8];
        } else {
            half8 z = {};
            *(half8*)&Alds[r][c8] = z;
        }
    }
    __syncthreads();

    int w = tid >> 6;          // wave id: rows [w*16, w*16+16)
    int lane = tid & 63;
    int lr = lane & 15;        // A-row within strip / C-col within frag
    int lk = lane >> 4;        // k-group (0..3)

    floatx4 acc[8];
    #pragma unroll
    for (int f = 0; f < 8; ++f) acc[f] = (floatx4){0.f, 0.f, 0.f, 0.f};

    #pragma unroll
    for (int kc = 0; kc < 4; ++kc) {
        half8 a = *(const half8*)&Alds[w * 16 + lr][kc * 32 + lk * 8];
        #pragma unroll
        for (int f = 0; f < 8; ++f) {
            half8 bb = *(const half8*)&Blds[f * 16 + lr][kc * 32 + lk * 8];
            acc[f] = __builtin_amdgcn_mfma_f32_16x16x32_f16(a, bb, acc[f], 0, 0, 0);
        }
    }

    // scatter: D layout col = lane&15, row = (lane>>4)*4 + j
    const int* oi = out_idx + (size_t)k * MM + m0;
    int mb = w * 16 + lk * 4;
    #pragma unroll
    for (int j = 0; j < 4; ++j) {
        int m = m0 + mb + j;
        if (m < MM) {
            int o = oi[mb + j];
            float* orow = out + (size_t)o * CC + lr;
            #pragma unroll
            for (int f = 0; f < 8; ++f)
                atomicAdd(orow + f * 16, acc[f][j]);
        }
    }
}

// ---------------- batchnorm stats ----------------
__global__ __launch_bounds__(256) void bn_stats_kernel(
    const float* __restrict__ in, float* __restrict__ stats, int nrows, int rpb) {
    int c = threadIdx.x & 127;
    int p = threadIdx.x >> 7;
    int r0 = blockIdx.x * rpb;
    int r1 = min(nrows, r0 + rpb);
    float s = 0.f, s2 = 0.f;
    for (int r = r0 + p; r < r1; r += 2) {
        float v = in[(size_t)r * CC + c];
        s += v; s2 += v * v;
    }
    __shared__ float ls[256], ls2[256];
    ls[threadIdx.x] = s; ls2[threadIdx.x] = s2;
    __syncthreads();
    if (p == 0) {
        atomicAdd(&stats[c],      ls[c] + ls[c + 128]);
        atomicAdd(&stats[CC + c], ls2[c] + ls2[c + 128]);
    }
}

__global__ void bn_finalize_kernel(
    const float* __restrict__ stats, const float* __restrict__ gamma,
    const float* __restrict__ beta, float* __restrict__ ss) {
    int c = threadIdx.x;
    if (c < CC) {
        float mean = stats[c] * (1.f / NN);
        float var = stats[CC + c] * (1.f / NN) - mean * mean;
        float sc = gamma[c] * rsqrtf(var + 1e-5f);
        ss[c] = sc;
        ss[CC + c] = beta[c] - mean * sc;
    }
}

// ---------------- fused BN+ReLU -> segment pool ----------------
__global__ __launch_bounds__(256) void pool_kernel(
    const float* __restrict__ in, const float* __restrict__ ss,
    const int* __restrict__ batch_id, float* __restrict__ pooled,
    int nrows, int rpb) {
    int c = threadIdx.x & 127;
    int p = threadIdx.x >> 7;
    float sc = ss[c], sh = ss[CC + c];
    int r0 = blockIdx.x * rpb;
    int r1 = min(nrows, r0 + rpb);
    float acc = 0.f; int cur = -1;
    for (int r = r0 + p; r < r1; r += 2) {
        int b = batch_id[r];
        float v = fmaxf(fmaf(in[(size_t)r * CC + c], sc, sh), 0.f);
        if (b != cur) {
            if (cur >= 0) atomicAdd(&pooled[cur * CC + c], acc);
            cur = b; acc = 0.f;
        }
        acc += v;
    }
    if (cur >= 0) atomicAdd(&pooled[cur * CC + c], acc);
}

// ---------------- SE MLP (tiny, 1 block) ----------------
__global__ __launch_bounds__(256) void se_kernel(
    const float* __restrict__ pooled, const float* __restrict__ fc1,
    const float* __restrict__ fc2, float* __restrict__ se) {
    __shared__ float h[BBATCH][CRR];
    int tid = threadIdx.x;
    {
        int b = tid >> 5, j = tid & 31;
        float a = 0.f;
        for (int c = 0; c < CC; ++c) a += pooled[b * CC + c] * fc1[c * CRR + j];
        h[b][j] = fmaxf(a, 0.f);
    }
    __syncthreads();
    #pragma unroll
    for (int i = 0; i < 4; ++i) {
        int idx = tid + i * 256;
        int b = idx >> 7, c = idx & 127;
        float a = 0.f;
        #pragma unroll
        for (int j = 0; j < CRR; ++j) a += h[b][j] * fc2[j * CC + c];
        se[b * CC + c] = 1.f / (1.f + expf(-a));
    }
}

// ---------------- fused BN+ReLU+SE-scale -> f16 ----------------
__global__ __launch_bounds__(256) void scale_convert_kernel(
    const float* __restrict__ in, const float* __restrict__ ss,
    const float* __restrict__ se, const int* __restrict__ batch_id,
    _Float16* __restrict__ outh) {
    int i = blockIdx.x * 256 + threadIdx.x;              // one float4 per thread
    if (i >= NN * (CC / 4)) return;
    int row = i >> 5;
    int q = i & 31;
    int b = batch_id[row];
    float4 v  = ((const float4*)in)[i];
    float4 sc = ((const float4*)ss)[q];
    float4 sh = ((const float4*)(ss + CC))[q];
    float4 s  = ((const float4*)(se + (size_t)b * CC))[q];
    Half4 o;
    o.x = (_Float16)(fmaxf(fmaf(v.x, sc.x, sh.x), 0.f) * s.x);
    o.y = (_Float16)(fmaxf(fmaf(v.y, sc.y, sh.y), 0.f) * s.y);
    o.z = (_Float16)(fmaxf(fmaf(v.z, sc.z, sh.z), 0.f) * s.z);
    o.w = (_Float16)(fmaxf(fmaf(v.w, sc.w, sh.w), 0.f) * s.w);
    ((Half4*)outh)[i] = o;
}

// ---------------- final: BN2 + residual + ReLU (in place) ----------------
__global__ __launch_bounds__(256) void final_kernel(
    float* __restrict__ out, const float* __restrict__ ss,
    const float* __restrict__ x) {
    int i = blockIdx.x * 256 + threadIdx.x;
    if (i >= NN * (CC / 4)) return;
    int q = i & 31;
    float4 v  = ((float4*)out)[i];
    float4 r  = ((const float4*)x)[i];
    float4 sc = ((const float4*)ss)[q];
    float4 sh = ((const float4*)(ss + CC))[q];
    float4 o;
    o.x = fmaxf(fmaf(v.x, sc.x, sh.x) + r.x, 0.f);
    o.y = fmaxf(fmaf(v.y, sc.y, sh.y) + r.y, 0.f);
    o.z = fmaxf(fmaf(v.z, sc.z, sh.z) + r.z, 0.f);
    o.w = fmaxf(fmaf(v.w, sc.w, sh.w) + r.w, 0.f);
    ((float4*)out)[i] = o;
}

extern "C" void kernel_launch(void* const* d_in, const int* in_sizes, int n_in,
                              void* d_out, int out_size, void* d_ws, size_t ws_size,
                              hipStream_t stream) {
    const float* x        = (const float*)d_in[0];
    const int*   batch_id = (const int*)d_in[1];
    const int*   in_idx   = (const int*)d_in[2];
    const int*   out_idx  = (const int*)d_in[3];
    const float* W1       = (const float*)d_in[4];
    const float* W2       = (const float*)d_in[5];
    const float* fc1      = (const float*)d_in[6];
    const float* fc2      = (const float*)d_in[7];
    const float* gamma1   = (const float*)d_in[8];
    const float* beta1    = (const float*)d_in[9];
    const float* gamma2   = (const float*)d_in[10];
    const float* beta2    = (const float*)d_in[11];
    float* out = (float*)d_out;

    char* ws = (char*)d_ws;
    size_t off = 0;
    auto alloc = [&](size_t bytes) {
        void* p = ws + off;
        off = (off + bytes + 255) & ~(size_t)255;
        return p;
    };
    _Float16* xh    = (_Float16*)alloc((size_t)NN * CC * 2);
    _Float16* w1t   = (_Float16*)alloc((size_t)KK * CC * CC * 2);
    _Float16* w2t   = (_Float16*)alloc((size_t)KK * CC * CC * 2);
    float*    out1  = (float*)alloc((size_t)NN * CC * 4);
    float*    stats1 = (float*)alloc(2 * CC * 4);
    float*    ss1    = (float*)alloc(2 * CC * 4);
    float*    stats2 = (float*)alloc(2 * CC * 4);
    float*    ss2    = (float*)alloc(2 * CC * 4);
    float*    pooled = (float*)alloc(BBATCH * CC * 4);
    float*    sebuf  = (float*)alloc(BBATCH * CC * 4);
    // out1h aliases xh: xh is dead after conv1, out1h written after conv1 completes
    _Float16* out1h = xh;

    hipMemsetAsync(out1,   0, (size_t)NN * CC * 4, stream);
    hipMemsetAsync(out,    0, (size_t)NN * CC * 4, stream);
    hipMemsetAsync(stats1, 0, 2 * CC * 4, stream);
    hipMemsetAsync(stats2, 0, 2 * CC * 4, stream);
    hipMemsetAsync(pooled, 0, BBATCH * CC * 4, stream);

    int elem4 = NN * (CC / 4);                  // 3,200,000
    int g_e4 = (elem4 + 255) / 256;             // 12500
    int g_w = (KK * CC * CC + 255) / 256;       // 1728
    int rpb = (NN + 511) / 512;                 // 196

    convert_x_kernel<<<g_e4, 256, 0, stream>>>(x, xh);
    convert_w_kernel<<<g_w, 256, 0, stream>>>(W1, w1t);
    convert_w_kernel<<<g_w, 256, 0, stream>>>(W2, w2t);

    conv_kernel<<<KK * NBLK, 256, 0, stream>>>(xh, w1t, in_idx, out_idx, out1);

    bn_stats_kernel<<<512, 256, 0, stream>>>(out1, stats1, NN, rpb);
    bn_finalize_kernel<<<1, 128, 0, stream>>>(stats1, gamma1, beta1, ss1);
    pool_kernel<<<512, 256, 0, stream>>>(out1, ss1, batch_id, pooled, NN, rpb);
    se_kernel<<<1, 256, 0, stream>>>(pooled, fc1, fc2, sebuf);
    scale_convert_kernel<<<g_e4, 256, 0, stream>>>(out1, ss1, sebuf, batch_id, out1h);

    conv_kernel<<<KK * NBLK, 256, 0, stream>>>(out1h, w2t, in_idx, out_idx, out);

    bn_stats_kernel<<<512, 256, 0, stream>>>(out, stats2, NN, rpb);
    bn_finalize_kernel<<<1, 128, 0, stream>>>(stats2, gamma2, beta2, ss2);
    final_kernel<<<g_e4, 256, 0, stream>>>(out, ss2, x);
}